// Round 1
// baseline (39.491 us; speedup 1.0000x reference)
//
#include <hip/hip_runtime.h>

// PSANet COLLECT forward, N=1, H=W=60.
//   out[oh*60+ow][h][w] = x[(oh+59-h)*119 + (ow+59-w)][h][w]
// One workgroup per (oh, h). All input needed by that WG is the slab
//   x[a*119 + b][h][0..59],  a = oh-h+59 (fixed),  b in [0,119)
// = 119 rows x 60 floats = 28.56 KB -> staged in LDS via float4 loads.
// Output tile (ow,w) in [0,60)^2 written coalesced (contiguous in w).

#define CH_STRIDE 3600   // H*W floats per channel

__global__ __launch_bounds__(256) void psa_collect_kernel(
    const float* __restrict__ x, float* __restrict__ out) {

    __shared__ float lds[119 * 60];   // 28560 B

    const int blk = blockIdx.x;       // oh*60 + h
    const int oh  = blk / 60;
    const int h   = blk - oh * 60;
    const int a   = oh - h + 59;      // channel-grid row, in [0,118]
    const int tid = threadIdx.x;

    // ---- Phase 1: global -> LDS, 1785 float4 (119 rows x 15 float4) ----
    const float* src = x + (size_t)a * 119 * CH_STRIDE + h * 60;
    for (int l = tid; l < 119 * 15; l += 256) {
        const int b = l / 15;              // channel-grid col (row in LDS)
        const int j = l - b * 15;          // float4 index within row
        const float4 v =
            *reinterpret_cast<const float4*>(src + (size_t)b * CH_STRIDE + j * 4);
        *reinterpret_cast<float4*>(&lds[b * 60 + j * 4]) = v;
    }
    __syncthreads();

    // ---- Phase 2: LDS -> global, coalesced in w ----
    // out channel = oh*60 + ow, spatial row h. b = ow - w + 59.
    float* dst = out + (size_t)(oh * 60) * CH_STRIDE + h * 60;
    for (int m = tid; m < 3600; m += 256) {
        const int ow = m / 60;
        const int w  = m - ow * 60;
        dst[(size_t)ow * CH_STRIDE + w] = lds[(ow - w + 59) * 60 + w];
    }
}

extern "C" void kernel_launch(void* const* d_in, const int* in_sizes, int n_in,
                              void* d_out, int out_size, void* d_ws, size_t ws_size,
                              hipStream_t stream) {
    const float* x = (const float*)d_in[0];
    float* out = (float*)d_out;
    // 3600 workgroups: one per (oh, h) pair.
    psa_collect_kernel<<<dim3(3600), dim3(256), 0, stream>>>(x, out);
}

// Round 2
// 32.300 us; speedup vs baseline: 1.2226x; 1.2226x over previous
//
#include <hip/hip_runtime.h>

// PSANet COLLECT forward, N=1, H=W=60.
//   out[oh*60+ow][h][w] = x[(oh+59-h)*119 + (ow+59-w)][h][w]
// One workgroup per (oh, h); a = oh-h+59 fixed. Needed input:
//   x[a*119 + b][h][w] for b in [0,119), w in [max(0,59-b), min(60,119-b))
// (the parallelogram b+w in [59,118]). We stage ONLY those segments,
// rounded to aligned float4, into LDS (945 float4/WG vs 1785 for the
// full box -> read traffic 54.4 MB vs 102.8 MB; used set = 51.8 MB).
// Output 60x60 tile written as float4 (coalesced, contiguous in w).

#define CH_STRIDE 3600   // H*W floats per channel

__global__ __launch_bounds__(256) void psa_collect_kernel(
    const float* __restrict__ x, float* __restrict__ out) {

    __shared__ float lds[119 * 60];   // 28560 B

    const int blk = blockIdx.x;       // oh*60 + h
    const int oh  = blk / 60;
    const int h   = blk - oh * 60;
    const int a   = oh - h + 59;      // channel-grid row, in [0,118]
    const int tid = threadIdx.x;

    // ---- Phase 1: global -> LDS, only the used parallelogram ----
    const float* src = x + (size_t)a * 119 * CH_STRIDE + h * 60;
    for (int l = tid; l < 119 * 15; l += 256) {
        const int b  = l / 15;             // channel-grid col (row in LDS)
        const int j4 = (l - b * 15) * 4;   // float index within row
        const int w0 = (b < 59) ? (59 - b) : 0;        // first used w
        const int w1 = (b < 59) ? 60 : (119 - b);      // one past last used w
        if (j4 < w1 && j4 + 4 > w0) {
            const float4 v =
                *reinterpret_cast<const float4*>(src + (size_t)b * CH_STRIDE + j4);
            *reinterpret_cast<float4*>(&lds[b * 60 + j4]) = v;
        }
    }
    __syncthreads();

    // ---- Phase 2: LDS -> global, float4 stores, coalesced in w ----
    // out channel = oh*60 + ow, spatial row h. lds addr = (ow+59)*60 - 59*w.
    float* dst = out + (size_t)(oh * 60) * CH_STRIDE + h * 60;
    for (int m = tid; m < 900; m += 256) {
        const int ow   = m / 15;
        const int w    = (m - ow * 15) * 4;
        const int base = (ow + 59) * 60;
        float4 v;
        v.x = lds[base - 59 * w];
        v.y = lds[base - 59 * (w + 1)];
        v.z = lds[base - 59 * (w + 2)];
        v.w = lds[base - 59 * (w + 3)];
        *reinterpret_cast<float4*>(dst + (size_t)ow * CH_STRIDE + w) = v;
    }
}

extern "C" void kernel_launch(void* const* d_in, const int* in_sizes, int n_in,
                              void* d_out, int out_size, void* d_ws, size_t ws_size,
                              hipStream_t stream) {
    const float* x = (const float*)d_in[0];
    float* out = (float*)d_out;
    // 3600 workgroups: one per (oh, h) pair.
    psa_collect_kernel<<<dim3(3600), dim3(256), 0, stream>>>(x, out);
}

// Round 3
// 30.968 us; speedup vs baseline: 1.2752x; 1.0430x over previous
//
#include <hip/hip_runtime.h>

// PSANet COLLECT forward, N=1, H=W=60.
//   out[oh*60+ow][h][w] = x[(oh+59-h)*119 + (ow+59-w)][h][w]
//
// WG per (oh, h-pair). For each h: slab a = oh+59-h, load trimmed
// parallelogram rows (b, w in [max(0,59-b), min(60,119-b))) and scatter
// COMPACTLY into lds[hh][ow*60+w] where ow = b+w-59 (bijective).
// 2 x 14.4 KB LDS. Phase 2: contiguous float4 LDS reads, 480 B
// contiguous stores per output channel (rows h0,h0+1).
// XCD-chunked block swizzle: consecutive logical blocks -> same XCD
// so shared read/write boundary sectors merge in one L2.

#define CH_STRIDE 3600   // H*W floats per channel

__global__ __launch_bounds__(256) void psa_collect_kernel(
    const float* __restrict__ x, float* __restrict__ out) {

    __shared__ float lds[2][3600];    // 28.8 KB, compact parallelogram

    // hw blockIdx -> logical block, XCD-chunked (1800 = 8 XCDs * 225)
    int l = blockIdx.x;
    l = (l & 7) * 225 + (l >> 3);
    const int oh = l / 30;
    const int hp = l - oh * 30;
    const int h0 = hp * 2;
    const int tid = threadIdx.x;

    // ---- Phase 1: global -> compact LDS ----
    for (int hh = 0; hh < 2; ++hh) {
        const int h = h0 + hh;
        const int a = oh + 59 - h;                  // channel-grid row
        const float* src = x + (size_t)a * 119 * CH_STRIDE + h * 60;
        for (int t = tid; t < 119 * 15; t += 256) {
            const int b  = t / 15;                  // channel-grid col
            const int j4 = (t - b * 15) * 4;        // first w of this float4
            const int w0 = (b < 59) ? (59 - b) : 0;
            const int w1 = (b < 59) ? 60 : (119 - b);
            if (j4 < w1 && j4 + 4 > w0) {
                const float4 v =
                    *reinterpret_cast<const float4*>(src + (size_t)b * CH_STRIDE + j4);
                const float* ve = reinterpret_cast<const float*>(&v);
#pragma unroll
                for (int e = 0; e < 4; ++e) {
                    const int w = j4 + e;
                    const int d = b + w - 59;       // = ow, in [0,60) iff used
                    if ((unsigned)d < 60u) lds[hh][d * 60 + w] = ve[e];
                }
            }
        }
    }
    __syncthreads();

    // ---- Phase 2: LDS -> global, 480 B contiguous per output channel ----
    float* dst = out + (size_t)(oh * 60) * CH_STRIDE + h0 * 60;
    for (int m = tid; m < 1800; m += 256) {
        const int ow = m / 30;
        const int r  = m - ow * 30;                 // 0..29: (hh, j4)
        const int hh = r / 15;
        const int j4 = (r - hh * 15) * 4;
        const float4 v = *reinterpret_cast<const float4*>(&lds[hh][ow * 60 + j4]);
        *reinterpret_cast<float4*>(dst + (size_t)ow * CH_STRIDE + hh * 60 + j4) = v;
    }
}

extern "C" void kernel_launch(void* const* d_in, const int* in_sizes, int n_in,
                              void* d_out, int out_size, void* d_ws, size_t ws_size,
                              hipStream_t stream) {
    const float* x = (const float*)d_in[0];
    float* out = (float*)d_out;
    // 1800 workgroups: one per (oh, h-pair).
    psa_collect_kernel<<<dim3(1800), dim3(256), 0, stream>>>(x, out);
}

// Round 5
// 29.939 us; speedup vs baseline: 1.3190x; 1.0344x over previous
//
#include <hip/hip_runtime.h>

// PSANet COLLECT forward, N=1, H=W=60.
//   out[oh*60+ow][h][w] = x[(oh+59-h)*119 + (ow+59-w)][h][w]
//
// One WG per (oh, h-pair) -- 1800 WGs, 512 threads each.
// For each h: slab a = oh+59-h, load trimmed parallelogram rows
// (b, w in [max(0,59-b), min(60,119-b))) and scatter COMPACTLY into
// lds[hh][ow*60+w], ow = b+w-59 (bijective). LDS 28.8 KB.
// Occupancy: 512 thr = 8 waves/WG; 4 WGs/CU -> 32 waves/CU (full).
// Phase 2: contiguous float4 LDS reads, 480 B contiguous stores per
// output channel. XCD-chunked swizzle (1800 = 8*225, bijective).

#define CH_STRIDE 3600   // H*W floats per channel

__global__ __launch_bounds__(512) void psa_collect_kernel(
    const float* __restrict__ x, float* __restrict__ out) {

    __shared__ float lds[2][3600];    // 28.8 KB, compact parallelogram

    // XCD-chunked bijective swizzle: 1800 = 8 * 225.
    int l = blockIdx.x;
    l = (l & 7) * 225 + (l >> 3);
    const int oh = l / 30;            // [0,60)
    const int hp = l - oh * 30;       // [0,30)
    const int h0 = hp * 2;
    const int tid = threadIdx.x;

    // ---- Phase 1: global -> compact LDS (trimmed parallelogram) ----
    for (int hh = 0; hh < 2; ++hh) {
        const int h = h0 + hh;
        const int a = oh + 59 - h;                  // channel-grid row
        const float* src = x + (size_t)a * 119 * CH_STRIDE + h * 60;
        for (int t = tid; t < 119 * 15; t += 512) {
            const int b  = t / 15;                  // channel-grid col
            const int j4 = (t - b * 15) * 4;        // first w of this float4
            const int w0 = (b < 59) ? (59 - b) : 0;
            const int w1 = (b < 59) ? 60 : (119 - b);
            if (j4 < w1 && j4 + 4 > w0) {
                const float4 v =
                    *reinterpret_cast<const float4*>(src + (size_t)b * CH_STRIDE + j4);
                const float* ve = reinterpret_cast<const float*>(&v);
#pragma unroll
                for (int e = 0; e < 4; ++e) {
                    const int w = j4 + e;
                    const int d = b + w - 59;       // = ow, in [0,60) iff used
                    if ((unsigned)d < 60u) lds[hh][d * 60 + w] = ve[e];
                }
            }
        }
    }
    __syncthreads();

    // ---- Phase 2: LDS -> global, 480 B contiguous per output channel ----
    float* dst = out + (size_t)(oh * 60) * CH_STRIDE + h0 * 60;
    for (int m = tid; m < 1800; m += 512) {
        const int ow = m / 30;
        const int r  = m - ow * 30;                 // 0..29: (hh, j4)
        const int hh = r / 15;
        const int j4 = (r - hh * 15) * 4;
        const float4 v = *reinterpret_cast<const float4*>(&lds[hh][ow * 60 + j4]);
        *reinterpret_cast<float4*>(dst + (size_t)ow * CH_STRIDE + hh * 60 + j4) = v;
    }
}

extern "C" void kernel_launch(void* const* d_in, const int* in_sizes, int n_in,
                              void* d_out, int out_size, void* d_ws, size_t ws_size,
                              hipStream_t stream) {
    const float* x = (const float*)d_in[0];
    float* out = (float*)d_out;
    // 1800 workgroups of 512 threads: one per (oh, h-pair).
    psa_collect_kernel<<<dim3(1800), dim3(512), 0, stream>>>(x, out);
}